// Round 4
// baseline (343.978 us; speedup 1.0000x reference)
//
#include <hip/hip_runtime.h>
#include <hip/hip_fp16.h>

#define BB 32
#define NI 2048
#define NK 64
#define KD 2048       // caps_n * caps_dim
#define NL 16
#define IT 8          // i's per conv block
#define NTC (NI/IT)   // 256 conv i-chunks
#define RCH 32        // i's per route block
#define NRC (NI/RCH)  // 64 route chunks
#define EPSF 1e-7f

typedef _Float16 h2 __attribute__((ext_vector_type(2)));
union UH2  { unsigned u; h2 h; };
union U4H8 { uint4 u4; h2 h[4]; };

static __device__ __forceinline__ float dot2f(h2 a, h2 b, float c) {
#if __has_builtin(__builtin_amdgcn_fdot2)
  return __builtin_amdgcn_fdot2(a, b, c, false);
#else
  return c + (float)a[0] * (float)b[0] + (float)a[1] * (float)b[1];
#endif
}

static __device__ __forceinline__ h2 pack2(float x, float y) {
  h2 r; r[0] = (_Float16)x; r[1] = (_Float16)y; return r;
}

// K1: u_hat[b][i][cell] f16 = sum_l W[i][cell][l] * x[b][i][l], fused round-0
// partial (c = 1/64 uniform). 512 threads; block = (i-chunk of 8) x (cell-half
// of 1024); thread owns cells c0=half*1024+2t, +1. 2 blocks/CU, ~100 VGPR.
__global__ __launch_bounds__(512, 4) void k_conv(const float* __restrict__ x,
                                                 const float* __restrict__ W,
                                                 __half* __restrict__ uhat,
                                                 __half* __restrict__ part) {
  const int blk = blockIdx.x, half = blockIdx.y, t = threadIdx.x;
  const int i0 = blk * IT;
  const int c0 = half * 1024 + 2 * t;
  __shared__ h2 xs[IT][BB][8];
  for (int q = t; q < IT * BB * 8; q += 512) {
    const int l2 = q & 7, b = (q >> 3) & 31, ii = q >> 8;
    const float2 f = *(const float2*)&x[((size_t)b * NI + (i0 + ii)) * NL + 2 * l2];
    xs[ii][b][l2] = pack2(f.x, f.y);
  }
  __syncthreads();

  float sacc0[BB], sacc1[BB];
  #pragma unroll
  for (int b = 0; b < BB; ++b) { sacc0[b] = 0.f; sacc1[b] = 0.f; }

  for (int ii = 0; ii < IT; ++ii) {
    const float* Wp = W + ((size_t)(i0 + ii) * KD + c0) * NL;
    h2 w0[8], w1[8];
    #pragma unroll
    for (int q = 0; q < 4; ++q) {
      const float4 f = *(const float4*)(Wp + 4 * q);
      w0[2 * q] = pack2(f.x, f.y); w0[2 * q + 1] = pack2(f.z, f.w);
    }
    #pragma unroll
    for (int q = 0; q < 4; ++q) {
      const float4 f = *(const float4*)(Wp + NL + 4 * q);
      w1[2 * q] = pack2(f.x, f.y); w1[2 * q + 1] = pack2(f.z, f.w);
    }
    #pragma unroll
    for (int b = 0; b < BB; ++b) {
      U4H8 ux0, ux1;
      ux0.u4 = *(const uint4*)&xs[ii][b][0];
      ux1.u4 = *(const uint4*)&xs[ii][b][4];
      float u0 = 0.f, u1 = 0.f;
      #pragma unroll
      for (int j = 0; j < 4; ++j) {
        u0 = dot2f(w0[j], ux0.h[j], u0); u0 = dot2f(w0[4 + j], ux1.h[j], u0);
        u1 = dot2f(w1[j], ux0.h[j], u1); u1 = dot2f(w1[4 + j], ux1.h[j], u1);
      }
      UH2 p; p.h = pack2(u0, u1);
      *(unsigned*)&uhat[((size_t)b * NI + (i0 + ii)) * KD + c0] = p.u;
      sacc0[b] += u0; sacc1[b] += u1;
    }
  }
  #pragma unroll
  for (int b = 0; b < BB; ++b) {
    UH2 p; p.h = pack2(sacc0[b] * (1.f / 64.f), sacc1[b] * (1.f / 64.f));
    *(unsigned*)&part[((size_t)b * NTC + blk) * KD + c0] = p.u;
  }
}

// Routing round: read u_hat, agreement logits = u . vin, softmax over k=64
// (no max-subtract; logits bounded), weighted partial accumulate.
// grid (NRC, BB), 256 threads; thread owns cells 8t..8t+7 (k = t>>2).
__global__ __launch_bounds__(256) void k_route(const __half* __restrict__ uhat,
                                               const float* __restrict__ vin,
                                               __half* __restrict__ part) {
  const int ch = blockIdx.x, b = blockIdx.y, t = threadIdx.x;
  const int lane = t & 63, wv = t >> 6;
  __shared__ float ssum[2][4];
  float vr[8];
  *(float4*)&vr[0] = *(const float4*)&vin[(size_t)b * KD + 8 * t];
  *(float4*)&vr[4] = *(const float4*)&vin[(size_t)b * KD + 8 * t + 4];
  float sacc[8];
  #pragma unroll
  for (int j = 0; j < 8; ++j) sacc[j] = 0.f;

  const __half* up = uhat + ((size_t)b * NI + (size_t)ch * RCH) * KD + 8 * t;
  U4H8 cur; cur.u4 = *(const uint4*)up;
  for (int il = 0; il < RCH; ++il) {
    U4H8 nxt;
    if (il + 1 < RCH) nxt.u4 = *(const uint4*)(up + (size_t)(il + 1) * KD);
    float uf[8];
    #pragma unroll
    for (int j = 0; j < 4; ++j) {
      uf[2 * j] = (float)cur.h[j][0];
      uf[2 * j + 1] = (float)cur.h[j][1];
    }
    float ag = 0.f;
    #pragma unroll
    for (int j = 0; j < 8; ++j) ag += uf[j] * vr[j];
    ag += __shfl_xor(ag, 1);
    ag += __shfl_xor(ag, 2);            // full dot over d=32 (4 threads per k)
    const float e = __expf(ag);
    float s = e;
    s += __shfl_xor(s, 4);  s += __shfl_xor(s, 8);
    s += __shfl_xor(s, 16); s += __shfl_xor(s, 32);   // sum over 16 k's in wave
    if (lane == 0) ssum[il & 1][wv] = s;
    __syncthreads();
    const float stot = ssum[il & 1][0] + ssum[il & 1][1] +
                       ssum[il & 1][2] + ssum[il & 1][3];
    const float c = e / stot;
    #pragma unroll
    for (int j = 0; j < 8; ++j) sacc[j] += c * uf[j];
    cur = nxt;
  }
  U4H8 o;
  o.h[0] = pack2(sacc[0], sacc[1]); o.h[1] = pack2(sacc[2], sacc[3]);
  o.h[2] = pack2(sacc[4], sacc[5]); o.h[3] = pack2(sacc[6], sacc[7]);
  *(uint4*)&part[((size_t)b * NRC + ch) * KD + 8 * t] = o.u4;
}

// Reduce partials over nch chunks, squash over d=32; optional vprev add
// (round-1 output becomes v0+v1 for the linear-agreement trick).
__global__ __launch_bounds__(256) void k_reduce(const __half* __restrict__ part,
                                                int nch,
                                                const float* __restrict__ vprev,
                                                float* __restrict__ vout) {
  const int g = blockIdx.x, b = blockIdx.y, t = threadIdx.x;
  const int p = g * 256 + t;            // h2-pair index: cells 2p, 2p+1
  const h2* pp = (const h2*)part;
  const size_t base = (size_t)b * nch * (KD / 2) + p;
  float s0 = 0.f, s1 = 0.f;
  for (int ch = 0; ch < nch; ++ch) {
    const h2 v = pp[base + (size_t)ch * (KD / 2)];
    s0 += (float)v[0]; s1 += (float)v[1];
  }
  float sq = s0 * s0 + s1 * s1;
  sq += __shfl_xor(sq, 1); sq += __shfl_xor(sq, 2);
  sq += __shfl_xor(sq, 4); sq += __shfl_xor(sq, 8);
  sq += EPSF;
  const float sc = sqrtf(sq) / (1.f + sq);
  float r0 = s0 * sc, r1 = s1 * sc;
  if (vprev != nullptr) {
    r0 += vprev[(size_t)b * KD + 2 * p];
    r1 += vprev[(size_t)b * KD + 2 * p + 1];
  }
  *(float2*)&vout[(size_t)b * KD + 2 * p] = make_float2(r0, r1);
}

extern "C" void kernel_launch(void* const* d_in, const int* in_sizes, int n_in,
                              void* d_out, int out_size, void* d_ws, size_t ws_size,
                              hipStream_t stream) {
  const float* x = (const float*)d_in[0];   // [32, 2048, 16]
  const float* W = (const float*)d_in[1];   // [2048, 64, 32, 16]
  float* out = (float*)d_out;               // [32, 64, 32]
  char* ws = (char*)d_ws;
  __half* uhat  = (__half*)ws;                                    // 268435456 B
  __half* part0 = (__half*)(ws + 268435456ull);                   // 33554432 B
  __half* partR = (__half*)(ws + 268435456ull + 33554432ull);     // 8388608 B
  float*  vA    = (float*)(ws + 268435456ull + 33554432ull + 8388608ull);
  float*  vB    = vA + (size_t)BB * KD;

  k_conv<<<dim3(NTC, 2), 512, 0, stream>>>(x, W, uhat, part0);
  k_reduce<<<dim3(4, BB), 256, 0, stream>>>(part0, NTC, nullptr, vA);  // vA = v0
  k_route<<<dim3(NRC, BB), 256, 0, stream>>>(uhat, vA, partR);         // u.v0
  k_reduce<<<dim3(4, BB), 256, 0, stream>>>(partR, NRC, vA, vB);       // vB = v0+v1
  k_route<<<dim3(NRC, BB), 256, 0, stream>>>(uhat, vB, partR);         // u.(v0+v1)
  k_reduce<<<dim3(4, BB), 256, 0, stream>>>(partR, NRC, nullptr, out); // out = v2
}